// Round 4
// baseline (1193.543 us; speedup 1.0000x reference)
//
#include <hip/hip_runtime.h>

#define N_TOKENS 131072
#define DIM 64
#define N_EMBED 1024
#define DECAYF 0.99f
#define OMDF 0.01f
#define EPSF 1e-5f
#define CHUNK 128

// Output layout (floats), reference return order:
// quantize_st [131072*64], diff [1], embed_ind [131072], new_embed [64*1024],
// new_cluster_size [1024], new_embed_avg [64*1024]
#define OFF_QST  ((size_t)0)
#define OFF_DIFF ((size_t)8388608)
#define OFF_IND  ((size_t)8388609)
#define OFF_NE   ((size_t)8519681)
#define OFF_NCS  ((size_t)8585217)
#define OFF_NEA  ((size_t)8586241)

// ws layout: floats then ints
// f[0] diff_sum, f[1] n_val, f[1026..66562) es, f[66562..132098) embedT,
// f[132098..133122) cnorm; ints at f-index 133632:
// cnt_i[1024], start_i[1024], cursor_i[1024], sorted[131072]
#define WS_DIFF   0
#define WS_NVAL   1
#define WS_ES     1026
#define WS_ET     66562
#define WS_CNORM  132098
#define WS_IWS    133632

__global__ __launch_bounds__(256) void vq_prep_transpose(
    const float* __restrict__ embed, float* __restrict__ embedT)
{
    int i = blockIdx.x * 256 + threadIdx.x;        // 65536 elems, coalesced read
    int d = i >> 10, e = i & 1023;
    embedT[e * DIM + d] = embed[i];
}

__global__ __launch_bounds__(256) void vq_prep_norm(
    const float* __restrict__ embedT, float* __restrict__ cnorm)
{
    int e = blockIdx.x * 256 + threadIdx.x;        // 1024
    const float4* c = (const float4*)(embedT + (size_t)e * DIM);
    float s = 0.f;
#pragma unroll
    for (int i = 0; i < 16; ++i) {
        float4 v = c[i];
        s = fmaf(v.x, v.x, s); s = fmaf(v.y, v.y, s);
        s = fmaf(v.z, v.z, s); s = fmaf(v.w, v.w, s);
    }
    cnorm[e] = s;
}

// T=1 token/thread, 512 blocks, embed chunk staged in LDS.
// Adds per-block LDS histogram, flushed with aggregated global int atomics.
__global__ __launch_bounds__(256) void vq_main(
    const float* __restrict__ x, const float* __restrict__ embedT,
    const float* __restrict__ cnorm, float* __restrict__ out,
    float* __restrict__ diff_sum, int* __restrict__ cnt_i)
{
    __shared__ float ec[CHUNK * DIM];   // 32 KB: chunk of codes, [code][d]
    __shared__ float cnc[CHUNK];        // chunk code norms
    __shared__ int   lhist[N_EMBED];    // 4 KB block histogram

    const int t = threadIdx.x;
    for (int i = t; i < N_EMBED; i += 256) lhist[i] = 0;

    const size_t n = (size_t)blockIdx.x * 256 + t;   // one token per thread
    float4 xq[16];
    {
        const float4* xv = (const float4*)(x + n * DIM);
#pragma unroll
        for (int i = 0; i < 16; ++i) xq[i] = xv[i];
    }

    float best = 3.4e38f;
    int bi = 0;

    for (int c = 0; c < N_EMBED; c += CHUNK) {
        __syncthreads();                               // prev chunk consumed / lhist init
        {   // stage CHUNK*64 floats = 2048 float4; 256 threads x 8 each
            const float4* src = (const float4*)(embedT + (size_t)c * DIM);
            float4* dst = (float4*)ec;
#pragma unroll
            for (int j = 0; j < (CHUNK * DIM / 4) / 256; ++j)
                dst[j * 256 + t] = src[j * 256 + t];
            if (t < CHUNK) cnc[t] = cnorm[c + t];
        }
        __syncthreads();

#pragma unroll 2
        for (int e = 0; e < CHUNK; ++e) {
            const float4* ev4 = (const float4*)(ec + e * DIM);
            float a0 = 0.f, a1 = 0.f, a2 = 0.f, a3 = 0.f;
#pragma unroll
            for (int i = 0; i < 16; ++i) {
                float4 ev = ev4[i];                    // wave-uniform addr -> LDS broadcast
                a0 = fmaf(xq[i].x, ev.x, a0);
                a1 = fmaf(xq[i].y, ev.y, a1);
                a2 = fmaf(xq[i].z, ev.z, a2);
                a3 = fmaf(xq[i].w, ev.w, a3);
            }
            float dist = fmaf(-2.f, (a0 + a1) + (a2 + a3), cnc[e]);
            if (dist < best) { best = dist; bi = c + e; }   // strict <: first-index ties
        }
    }

    out[OFF_IND + n] = (float)bi;
    atomicAdd(&lhist[bi], 1);                          // LDS atomic

    // epilogue: quantize (== selected code), diff partial
    float ds = 0.f;
    {
        const float4* qcol = (const float4*)(embedT + (size_t)bi * DIM);
        float4* qout = (float4*)(out + OFF_QST + n * DIM);
#pragma unroll
        for (int i = 0; i < 16; ++i) {
            float4 q = qcol[i];
            float4 xx = xq[i];
            float ex = q.x - xx.x, ey = q.y - xx.y, ez = q.z - xx.z, ew = q.w - xx.w;
            qout[i] = q;                              // x + stopgrad(q - x) == q numerically
            ds = fmaf(ex, ex, ds); ds = fmaf(ey, ey, ds);
            ds = fmaf(ez, ez, ds); ds = fmaf(ew, ew, ds);
        }
    }
#pragma unroll
    for (int o = 32; o > 0; o >>= 1) ds += __shfl_down(ds, o, 64);
    if ((t & 63) == 0) atomicAdd(diff_sum, ds);       // 2048 atomics total: negligible

    // flush histogram: one global int atomic per nonzero bin (~226/block avg)
    __syncthreads();
    for (int i = t; i < N_EMBED; i += 256) {
        int c = lhist[i];
        if (c) atomicAdd(&cnt_i[i], c);
    }
}

// single block, 1024 threads: exclusive prefix over cnt_i -> start_i, cursor_i
__global__ __launch_bounds__(1024) void vq_start(
    const int* __restrict__ cnt_i, int* __restrict__ start_i,
    int* __restrict__ cursor_i)
{
    __shared__ int sc[N_EMBED];
    int e = threadIdx.x;
    int c = cnt_i[e];
    sc[e] = c;
    __syncthreads();
#pragma unroll
    for (int off = 1; off < N_EMBED; off <<= 1) {
        int v = (e >= off) ? sc[e - off] : 0;
        __syncthreads();
        sc[e] += v;
        __syncthreads();
    }
    int excl = sc[e] - c;
    start_i[e] = excl;
    cursor_i[e] = excl;
}

// 512 blocks x 256: bin token ids into sorted[] by code.
// LDS rank + one global atomic per nonzero code per block to reserve a range.
__global__ __launch_bounds__(256) void vq_sort(
    const float* __restrict__ out, int* __restrict__ cursor_i,
    int* __restrict__ sorted)
{
    __shared__ int lh[N_EMBED];
    __shared__ int lbase[N_EMBED];
    int t = threadIdx.x;
    for (int i = t; i < N_EMBED; i += 256) lh[i] = 0;
    __syncthreads();
    int tok = blockIdx.x * 256 + t;
    int e = (int)out[OFF_IND + tok];                  // exact small ints in float
    int p = atomicAdd(&lh[e], 1);                     // within-block rank (LDS)
    __syncthreads();
    for (int i = t; i < N_EMBED; i += 256) {
        int c = lh[i];
        if (c) lbase[i] = atomicAdd(&cursor_i[i], c); // reserve [base, base+c)
    }
    __syncthreads();
    sorted[lbase[e] + p] = tok;
}

// 1024 blocks (one per code) x 256: sum x rows of the code's token range.
__global__ __launch_bounds__(256) void vq_sum(
    const float* __restrict__ x, const int* __restrict__ sorted,
    const int* __restrict__ start_i, const int* __restrict__ cnt_i,
    float* __restrict__ es)
{
    __shared__ float part[4][DIM];
    int e = blockIdx.x, t = threadIdx.x;
    int w = t >> 6, d = t & 63;
    int s = start_i[e], c = cnt_i[e];
    float acc = 0.f;
    for (int m = w; m < c; m += 4) {                  // wave-strided over matches
        int tok = sorted[s + m];                      // wave-uniform -> broadcast
        acc += x[(size_t)tok * DIM + d];              // 256B coalesced row read
    }
    part[w][d] = acc;
    __syncthreads();
    if (t < DIM)
        es[(size_t)e * DIM + t] =
            (part[0][t] + part[1][t]) + (part[2][t] + part[3][t]);
}

__global__ __launch_bounds__(1024) void vq_final1(
    const float* __restrict__ cluster_size, const int* __restrict__ cnt_i,
    const float* __restrict__ diff_sum, float* __restrict__ out,
    float* __restrict__ n_val)
{
    int e = threadIdx.x;                            // single block of 1024
    float ncs = cluster_size[e] * DECAYF + OMDF * (float)cnt_i[e];
    out[OFF_NCS + e] = ncs;
    __shared__ float red[16];
    float s = ncs;
#pragma unroll
    for (int o = 32; o > 0; o >>= 1) s += __shfl_down(s, o, 64);
    if ((e & 63) == 0) red[e >> 6] = s;
    __syncthreads();
    if (e == 0) {
        float nsum = 0.f;
#pragma unroll
        for (int i = 0; i < 16; ++i) nsum += red[i];
        *n_val = nsum;
        out[OFF_DIFF] = *diff_sum / (float)((size_t)N_TOKENS * DIM);
    }
}

__global__ __launch_bounds__(256) void vq_final2(
    const float* __restrict__ embed_avg, const float* __restrict__ es,
    const float* __restrict__ n_val, float* __restrict__ out)
{
    int i = blockIdx.x * 256 + threadIdx.x;         // 65536, [d][e] flat
    int e = i & 1023, d = i >> 10;
    float nea = embed_avg[i] * DECAYF + OMDF * es[(size_t)e * DIM + d];
    out[OFF_NEA + i] = nea;
    float ncs = out[OFF_NCS + e];
    float nsum = *n_val;
    float cs = (ncs + EPSF) / (nsum + (float)N_EMBED * EPSF) * nsum;
    out[OFF_NE + i] = nea / cs;
}

extern "C" void kernel_launch(void* const* d_in, const int* in_sizes, int n_in,
                              void* d_out, int out_size, void* d_ws, size_t ws_size,
                              hipStream_t stream)
{
    const float* x            = (const float*)d_in[0];
    const float* embed        = (const float*)d_in[1];
    const float* cluster_size = (const float*)d_in[2];
    const float* embed_avg    = (const float*)d_in[3];
    float* out = (float*)d_out;
    float* ws  = (float*)d_ws;

    float* diff_sum = ws + WS_DIFF;
    float* n_val    = ws + WS_NVAL;
    float* es       = ws + WS_ES;
    float* embedT   = ws + WS_ET;
    float* cnorm    = ws + WS_CNORM;
    int*   iws      = (int*)(ws + WS_IWS);
    int*   cnt_i    = iws;
    int*   start_i  = iws + N_EMBED;
    int*   cursor_i = iws + 2 * N_EMBED;
    int*   sorted   = iws + 3 * N_EMBED;

    hipMemsetAsync(diff_sum, 0, 2 * sizeof(float), stream);
    hipMemsetAsync(cnt_i, 0, N_EMBED * sizeof(int), stream);

    vq_prep_transpose<<<256, 256, 0, stream>>>(embed, embedT);
    vq_prep_norm<<<4, 256, 0, stream>>>(embedT, cnorm);
    vq_main<<<N_TOKENS / 256, 256, 0, stream>>>(x, embedT, cnorm, out, diff_sum, cnt_i);
    vq_start<<<1, 1024, 0, stream>>>(cnt_i, start_i, cursor_i);
    vq_sort<<<N_TOKENS / 256, 256, 0, stream>>>(out, cursor_i, sorted);
    vq_sum<<<N_EMBED, 256, 0, stream>>>(x, sorted, start_i, cnt_i, es);
    vq_final1<<<1, 1024, 0, stream>>>(cluster_size, cnt_i, diff_sum, out, n_val);
    vq_final2<<<256, 256, 0, stream>>>(embed_avg, es, n_val, out);
}

// Round 5
// 551.102 us; speedup vs baseline: 2.1657x; 2.1657x over previous
//
#include <hip/hip_runtime.h>

#define N_TOKENS 131072
#define DIM 64
#define N_EMBED 1024
#define DECAYF 0.99f
#define OMDF 0.01f
#define EPSF 1e-5f
#define CHUNK 128
#define SUM_TPB 128   // tokens per block in vq_sum (4 waves x 32)

// Output layout (floats), reference return order:
// quantize_st [131072*64], diff [1], embed_ind [131072], new_embed [64*1024],
// new_cluster_size [1024], new_embed_avg [64*1024]
#define OFF_QST  ((size_t)0)
#define OFF_DIFF ((size_t)8388608)
#define OFF_IND  ((size_t)8388609)
#define OFF_NE   ((size_t)8519681)
#define OFF_NCS  ((size_t)8585217)
#define OFF_NEA  ((size_t)8586241)

// ws layout: floats then ints
// f[0] diff_sum, f[1] n_val, f[1026..66562) es, f[66562..132098) embedT,
// f[132098..133122) cnorm; ints at f-index 133632:
// cnt_i[1024], start_i[1024], cursor_i[1024], sorted[131072], scode[131072]
#define WS_DIFF   0
#define WS_NVAL   1
#define WS_ES     1026
#define WS_ET     66562
#define WS_CNORM  132098
#define WS_IWS    133632

__global__ __launch_bounds__(256) void vq_prep_transpose(
    const float* __restrict__ embed, float* __restrict__ embedT)
{
    int i = blockIdx.x * 256 + threadIdx.x;        // 65536 elems, coalesced read
    int d = i >> 10, e = i & 1023;
    embedT[e * DIM + d] = embed[i];
}

__global__ __launch_bounds__(256) void vq_prep_norm(
    const float* __restrict__ embedT, float* __restrict__ cnorm)
{
    int e = blockIdx.x * 256 + threadIdx.x;        // 1024
    const float4* c = (const float4*)(embedT + (size_t)e * DIM);
    float s = 0.f;
#pragma unroll
    for (int i = 0; i < 16; ++i) {
        float4 v = c[i];
        s = fmaf(v.x, v.x, s); s = fmaf(v.y, v.y, s);
        s = fmaf(v.z, v.z, s); s = fmaf(v.w, v.w, s);
    }
    cnorm[e] = s;
}

// T=1 token/thread, 512 blocks, embed chunk staged in LDS.
// Per-block LDS histogram flushed with aggregated global int atomics.
__global__ __launch_bounds__(256) void vq_main(
    const float* __restrict__ x, const float* __restrict__ embedT,
    const float* __restrict__ cnorm, float* __restrict__ out,
    float* __restrict__ diff_sum, int* __restrict__ cnt_i)
{
    __shared__ float ec[CHUNK * DIM];   // 32 KB: chunk of codes, [code][d]
    __shared__ float cnc[CHUNK];        // chunk code norms
    __shared__ int   lhist[N_EMBED];    // 4 KB block histogram

    const int t = threadIdx.x;
    for (int i = t; i < N_EMBED; i += 256) lhist[i] = 0;

    const size_t n = (size_t)blockIdx.x * 256 + t;   // one token per thread
    float4 xq[16];
    {
        const float4* xv = (const float4*)(x + n * DIM);
#pragma unroll
        for (int i = 0; i < 16; ++i) xq[i] = xv[i];
    }

    float best = 3.4e38f;
    int bi = 0;

    for (int c = 0; c < N_EMBED; c += CHUNK) {
        __syncthreads();                               // prev chunk consumed / lhist init
        {   // stage CHUNK*64 floats = 2048 float4; 256 threads x 8 each
            const float4* src = (const float4*)(embedT + (size_t)c * DIM);
            float4* dst = (float4*)ec;
#pragma unroll
            for (int j = 0; j < (CHUNK * DIM / 4) / 256; ++j)
                dst[j * 256 + t] = src[j * 256 + t];
            if (t < CHUNK) cnc[t] = cnorm[c + t];
        }
        __syncthreads();

#pragma unroll 2
        for (int e = 0; e < CHUNK; ++e) {
            const float4* ev4 = (const float4*)(ec + e * DIM);
            float a0 = 0.f, a1 = 0.f, a2 = 0.f, a3 = 0.f;
#pragma unroll
            for (int i = 0; i < 16; ++i) {
                float4 ev = ev4[i];                    // wave-uniform addr -> LDS broadcast
                a0 = fmaf(xq[i].x, ev.x, a0);
                a1 = fmaf(xq[i].y, ev.y, a1);
                a2 = fmaf(xq[i].z, ev.z, a2);
                a3 = fmaf(xq[i].w, ev.w, a3);
            }
            float dist = fmaf(-2.f, (a0 + a1) + (a2 + a3), cnc[e]);
            if (dist < best) { best = dist; bi = c + e; }   // strict <: first-index ties
        }
    }

    out[OFF_IND + n] = (float)bi;
    atomicAdd(&lhist[bi], 1);                          // LDS atomic

    // epilogue: quantize (== selected code), diff partial
    float ds = 0.f;
    {
        const float4* qcol = (const float4*)(embedT + (size_t)bi * DIM);
        float4* qout = (float4*)(out + OFF_QST + n * DIM);
#pragma unroll
        for (int i = 0; i < 16; ++i) {
            float4 q = qcol[i];
            float4 xx = xq[i];
            float ex = q.x - xx.x, ey = q.y - xx.y, ez = q.z - xx.z, ew = q.w - xx.w;
            qout[i] = q;                              // x + stopgrad(q - x) == q numerically
            ds = fmaf(ex, ex, ds); ds = fmaf(ey, ey, ds);
            ds = fmaf(ez, ez, ds); ds = fmaf(ew, ew, ds);
        }
    }
#pragma unroll
    for (int o = 32; o > 0; o >>= 1) ds += __shfl_down(ds, o, 64);
    if ((t & 63) == 0) atomicAdd(diff_sum, ds);       // 2048 atomics total: negligible

    // flush histogram: one global int atomic per nonzero bin (~226/block avg)
    __syncthreads();
    for (int i = t; i < N_EMBED; i += 256) {
        int c = lhist[i];
        if (c) atomicAdd(&cnt_i[i], c);
    }
}

// single block, 1024 threads: exclusive prefix over cnt_i -> cursor_i
__global__ __launch_bounds__(1024) void vq_start(
    const int* __restrict__ cnt_i, int* __restrict__ cursor_i)
{
    __shared__ int sc[N_EMBED];
    int e = threadIdx.x;
    int c = cnt_i[e];
    sc[e] = c;
    __syncthreads();
#pragma unroll
    for (int off = 1; off < N_EMBED; off <<= 1) {
        int v = (e >= off) ? sc[e - off] : 0;
        __syncthreads();
        sc[e] += v;
        __syncthreads();
    }
    cursor_i[e] = sc[e] - c;
}

// 512 blocks x 256: bin token ids (and their code) into sorted[]/scode[].
__global__ __launch_bounds__(256) void vq_sort(
    const float* __restrict__ out, int* __restrict__ cursor_i,
    int* __restrict__ sorted, int* __restrict__ scode)
{
    __shared__ int lh[N_EMBED];
    __shared__ int lbase[N_EMBED];
    int t = threadIdx.x;
    for (int i = t; i < N_EMBED; i += 256) lh[i] = 0;
    __syncthreads();
    int tok = blockIdx.x * 256 + t;
    int e = (int)out[OFF_IND + tok];                  // exact small ints in float
    int p = atomicAdd(&lh[e], 1);                     // within-block rank (LDS)
    __syncthreads();
    for (int i = t; i < N_EMBED; i += 256) {
        int c = lh[i];
        if (c) lbase[i] = atomicAdd(&cursor_i[i], c); // reserve [base, base+c)
    }
    __syncthreads();
    int pos = lbase[e] + p;
    sorted[pos] = tok;
    scode[pos] = e;
}

// Token-balanced segment sum: 1024 blocks x 128 tokens. Wave lane = dim.
// Each wave scans 32 consecutive sorted slots, run-length accumulates,
// flushes at segment boundaries with global fp32 atomics (~1.3/wave).
__global__ __launch_bounds__(256) void vq_sum(
    const float* __restrict__ x, const int* __restrict__ sorted,
    const int* __restrict__ scode, float* __restrict__ es)
{
    __shared__ int ltok[SUM_TPB];
    __shared__ int lcode[SUM_TPB];
    const int t = threadIdx.x;
    const int base = blockIdx.x * SUM_TPB;
    if (t < SUM_TPB) {
        ltok[t]  = sorted[base + t];
        lcode[t] = scode[base + t];
    }
    __syncthreads();

    const int w = t >> 6, d = t & 63;
    const int i0 = w * (SUM_TPB / 4);                 // 32 tokens per wave
    int   cur = lcode[i0];
    float acc = 0.f;
#pragma unroll 4
    for (int i = i0; i < i0 + SUM_TPB / 4; ++i) {
        int e = lcode[i];                             // wave-uniform
        if (e != cur) {                               // uniform branch
            atomicAdd(&es[(size_t)cur * DIM + d], acc);
            acc = 0.f;
            cur = e;
        }
        acc += x[(size_t)ltok[i] * DIM + d];          // 256B coalesced row read
    }
    atomicAdd(&es[(size_t)cur * DIM + d], acc);
}

__global__ __launch_bounds__(1024) void vq_final1(
    const float* __restrict__ cluster_size, const int* __restrict__ cnt_i,
    const float* __restrict__ diff_sum, float* __restrict__ out,
    float* __restrict__ n_val)
{
    int e = threadIdx.x;                            // single block of 1024
    float ncs = cluster_size[e] * DECAYF + OMDF * (float)cnt_i[e];
    out[OFF_NCS + e] = ncs;
    __shared__ float red[16];
    float s = ncs;
#pragma unroll
    for (int o = 32; o > 0; o >>= 1) s += __shfl_down(s, o, 64);
    if ((e & 63) == 0) red[e >> 6] = s;
    __syncthreads();
    if (e == 0) {
        float nsum = 0.f;
#pragma unroll
        for (int i = 0; i < 16; ++i) nsum += red[i];
        *n_val = nsum;
        out[OFF_DIFF] = *diff_sum / (float)((size_t)N_TOKENS * DIM);
    }
}

__global__ __launch_bounds__(256) void vq_final2(
    const float* __restrict__ embed_avg, const float* __restrict__ es,
    const float* __restrict__ n_val, float* __restrict__ out)
{
    int i = blockIdx.x * 256 + threadIdx.x;         // 65536, [d][e] flat
    int e = i & 1023, d = i >> 10;
    float nea = embed_avg[i] * DECAYF + OMDF * es[(size_t)e * DIM + d];
    out[OFF_NEA + i] = nea;
    float ncs = out[OFF_NCS + e];
    float nsum = *n_val;
    float cs = (ncs + EPSF) / (nsum + (float)N_EMBED * EPSF) * nsum;
    out[OFF_NE + i] = nea / cs;
}

extern "C" void kernel_launch(void* const* d_in, const int* in_sizes, int n_in,
                              void* d_out, int out_size, void* d_ws, size_t ws_size,
                              hipStream_t stream)
{
    const float* x            = (const float*)d_in[0];
    const float* embed        = (const float*)d_in[1];
    const float* cluster_size = (const float*)d_in[2];
    const float* embed_avg    = (const float*)d_in[3];
    float* out = (float*)d_out;
    float* ws  = (float*)d_ws;

    float* diff_sum = ws + WS_DIFF;
    float* n_val    = ws + WS_NVAL;
    float* es       = ws + WS_ES;
    float* embedT   = ws + WS_ET;
    float* cnorm    = ws + WS_CNORM;
    int*   iws      = (int*)(ws + WS_IWS);
    int*   cnt_i    = iws;
    int*   cursor_i = iws + 2 * N_EMBED;
    int*   sorted   = iws + 3 * N_EMBED;
    int*   scode    = sorted + N_TOKENS;

    hipMemsetAsync(diff_sum, 0, 2 * sizeof(float), stream);
    hipMemsetAsync(es, 0, N_EMBED * DIM * sizeof(float), stream);   // atomic accumulator
    hipMemsetAsync(cnt_i, 0, N_EMBED * sizeof(int), stream);

    vq_prep_transpose<<<256, 256, 0, stream>>>(embed, embedT);
    vq_prep_norm<<<4, 256, 0, stream>>>(embedT, cnorm);
    vq_main<<<N_TOKENS / 256, 256, 0, stream>>>(x, embedT, cnorm, out, diff_sum, cnt_i);
    vq_start<<<1, 1024, 0, stream>>>(cnt_i, cursor_i);
    vq_sort<<<N_TOKENS / 256, 256, 0, stream>>>(out, cursor_i, sorted, scode);
    vq_sum<<<N_TOKENS / SUM_TPB, 256, 0, stream>>>(x, sorted, scode, es);
    vq_final1<<<1, 1024, 0, stream>>>(cluster_size, cnt_i, diff_sum, out, n_val);
    vq_final2<<<256, 256, 0, stream>>>(embed_avg, es, n_val, out);
}